// Round 15
// baseline (200.734 us; speedup 1.0000x reference)
//
#include <hip/hip_runtime.h>

typedef __attribute__((ext_vector_type(4))) float f32x4;
typedef __attribute__((ext_vector_type(8))) short short8;
typedef __attribute__((ext_vector_type(2))) unsigned uint2v;

#define E_DIM 512
#define HW    4096      // 64*64 spatial per batch
#define NT    32768     // total tokens
#define NTE   16777216  // NT*E_DIM elements (32 MiB as bf16)

// bf16 copies of in_proj_w (rows 0..1535) and out_proj_w (rows 1536..2047)
__device__ short g_wbf[2048 * E_DIM];

// round-to-nearest-even f32 -> bf16 bits
__device__ __forceinline__ short f2bf(float f) {
  union { float f; unsigned u; } v; v.f = f;
  unsigned u = v.u;
  u += 0x7fffu + ((u >> 16) & 1u);
  return (short)(u >> 16);
}
__device__ __forceinline__ unsigned pack_bf2(float lo, float hi) {
  return (unsigned)(unsigned short)f2bf(lo) | ((unsigned)(unsigned short)f2bf(hi) << 16);
}

// attn-kernel swizzle: [rows][64] bf16 tile, chunk ^= (row&7)
__device__ __forceinline__ int swzidx(int row, int k) {
  return row * 64 + (k ^ ((row & 7) << 3));
}

// ---- staged bf16 tile (gload_lds): 128B lines = 2 rows x 4 chunks,
// physical chunk = logical ^ (line&7)  -> 2-way (free) ds_read_b128 banks
__device__ __forceinline__ void chunk_map(int c, int& row, int& kc) {
  const int line = c >> 3;
  const int l = (c & 7) ^ (line & 7);
  row = line * 2 + (l >> 2);
  kc = l & 3;
}
__device__ __forceinline__ int tile_off(int row, int kc) {  // in shorts
  const int line = row >> 1;
  const int phys = (((row & 1) << 2) | kc) ^ (line & 7);
  return line * 64 + phys * 8;
}

// async global->LDS, 16B per lane; LDS dest = wave-uniform base (+lane*16 HW)
#define GLOAD16(g, l) __builtin_amdgcn_global_load_lds( \
    (const __attribute__((address_space(1))) void*)(g), \
    (__attribute__((address_space(3))) void*)(l), 16, 0, 0)

#define WAITVM(N) asm volatile("s_waitcnt vmcnt(" #N ")" ::: "memory")
#define LGKM0()   asm volatile("s_waitcnt lgkmcnt(0)" ::: "memory")
#define FULL_BAR() do { asm volatile("" ::: "memory"); \
  __builtin_amdgcn_s_barrier(); asm volatile("" ::: "memory"); } while (0)

// ---------------------------------------------------------------------------
// convert_w: f32 -> bf16 for both weight matrices into g_wbf
// ---------------------------------------------------------------------------
__global__ __launch_bounds__(256) void convert_w(
    const float* __restrict__ w_in, const float* __restrict__ w_out)
{
  const size_t off = ((size_t)blockIdx.x * 256 + threadIdx.x) * 8;
  const float* src = (off < 786432) ? (w_in + off) : (w_out + (off - 786432));
  f32x4 a = *(const f32x4*)src, b = *(const f32x4*)(src + 4);
  short8 s;
#pragma unroll
  for (int j = 0; j < 4; ++j) { s[j] = f2bf(a[j]); s[4 + j] = f2bf(b[j]); }
  *(short8*)&g_wbf[off] = s;
}

// ---------------------------------------------------------------------------
// proj: 128x128 tile, 256 thr (4 waves, 2x2), BK=32. TLP-first: LDS 40KB
// (A 2x8KB slots + B 3x8KB ring) + acc[4][4]=64 regs -> target 3-4 blocks/CU
// so barrier/vmcnt stalls overlap ACROSS blocks (m114 mechanism; the 256²
// 1-block/CU variant plateaued at 107-114us with nothing saturated).
// A: global f32 depth-2 (aX/aY) -> pack bf16 -> [16 fp][128 tok] u32 LDS,
//    4x ds_write_b64 chunk-XOR (R13/R14-validated layout, resized).
// B: global_load_lds 3-slot ring, issue-after-barrier 2 tiles ahead.
// Ledger identical to R14 (same per-step op counts): steady WAITVM(6).
// ---------------------------------------------------------------------------
__global__ __launch_bounds__(256) void proj_kernel(
    const float* __restrict__ Xq, const float* __restrict__ Xk,
    const float* __restrict__ Xv, const float* __restrict__ Bfull,
    short* __restrict__ Oq, short* __restrict__ Ok, short* __restrict__ Ov)
{
  // XCD-chunked bijective swizzle, 3072 = 8 * 384.
  // rr&3 = e-tile (fastest) -> 4 consecutive blocks share one X tok-tile (L2).
  const int wg  = blockIdx.x;
  const int swz = (wg & 7) * 384 + (wg >> 3);
  const int z = swz >> 10, rr = swz & 1023;
  const int e0 = (rr & 3) << 7, tok0 = (rr >> 2) << 7;

  const float* X  = (z == 0) ? Xq : (z == 1) ? Xk : Xv;
  const short* Wz = g_wbf + z * (E_DIM * E_DIM);
  const float* bias = Bfull + z * E_DIM;
  short* O = (z == 0) ? Oq : (z == 1) ? Ok : Ov;

  const int b   = tok0 >> 12;
  const int hw0 = tok0 & (HW - 1);
  const float* Xb = X + (size_t)b * E_DIM * HW + hw0;

  __shared__ unsigned ldsA[2 * 2048];   // 2 slots: [16 fp][128 tok] u32
  __shared__ short    ldsB[3 * 4096];   // 3 slots: 128x32 bf16, tile_off swz

  const int tid = threadIdx.x, lane = tid & 63, wv = tid >> 6;
  const int wm = wv >> 1, wn = wv & 1;
  const int lr = lane & 15, lg = lane >> 4;

  // ---- A staging map: thread handles f-rows (2fp, 2fp+1), tokens m*8..m*8+7
  const int fp = tid >> 4;           // 0..15
  const int m  = tid & 15;           // token-group
  const float* arow0 = Xb + (size_t)(2 * fp) * HW + m * 8;
  const int awbase = fp * 128 + ((m * 8) ^ ((fp >> 3) << 4));
  const int wkey   = ((m >> 2) & 3) ^ ((fp & 1) << 1);   // b64-chunk XOR

  // ---- B staging map (inverse of tile_off; rule #21)
  int r0, k0c, r1, k1c;
  chunk_map(tid, r0, k0c);
  chunk_map(256 + tid, r1, k1c);
  const short* sB0 = Wz + (size_t)(e0 + r0) * E_DIM + k0c * 8;
  const short* sB1 = Wz + (size_t)(e0 + r1) * E_DIM + k1c * 8;
  const int dc0 = wv * 512, dc1 = 2048 + wv * 512;   // shorts, wave-uniform

  // ---- fragment read offsets (match write swizzle; rule #21)
  int abase[4], boff[4];
#pragma unroll
  for (int i = 0; i < 4; ++i) {
    const int T = wm * 64 + i * 16 + lr;
    abase[i] = lg * 512 + ((T & ~7) ^ ((lg >> 1) << 4))
             + ((((T >> 1) & 3) ^ ((T >> 5) & 3)) << 1) + (T & 1);
  }
#pragma unroll
  for (int j = 0; j < 4; ++j) boff[j] = tile_off(wn * 64 + j * 16 + lr, lg);

  f32x4 acc[4][4];
#pragma unroll
  for (int i = 0; i < 4; ++i)
#pragma unroll
    for (int j = 0; j < 4; ++j) acc[i][j] = (f32x4){0.f, 0.f, 0.f, 0.f};

  f32x4 aX[4], aY[4];

#define ISSUE_A(dst, kt) do { \
    const float* ap = arow0 + (size_t)(kt) * (32 * HW); \
    dst[0] = *(const f32x4*)(ap);          dst[1] = *(const f32x4*)(ap + 4); \
    dst[2] = *(const f32x4*)(ap + HW);     dst[3] = *(const f32x4*)(ap + 4 + HW); \
  } while (0)

#define ISSUE_B(slot, kt) do { \
    const int ko2 = (kt) * 32, sb2 = (slot) * 4096; \
    GLOAD16(sB0 + ko2, &ldsB[sb2 + dc0]); \
    GLOAD16(sB1 + ko2, &ldsB[sb2 + dc1]); \
  } while (0)

  // 4x ds_write_b64, physical chunk = logical ^ wkey (balanced banks)
#define WRITE_A(slot, src) do { \
    unsigned* dA = &ldsA[(slot) * 2048 + awbase]; \
    _Pragma("unroll") \
    for (int c2 = 0; c2 < 4; ++c2) { \
      uint2v p_; \
      p_[0] = pack_bf2(src[(2*c2) >> 2][(2*c2) & 3],     src[2 + ((2*c2) >> 2)][(2*c2) & 3]); \
      p_[1] = pack_bf2(src[(2*c2+1) >> 2][(2*c2+1) & 3], src[2 + ((2*c2+1) >> 2)][(2*c2+1) & 3]); \
      *(uint2v*)(dA + ((c2 ^ wkey) << 1)) = p_; \
    } \
  } while (0)

#define COMPUTE(aslot, bslot) do { \
    const unsigned* pa = ldsA + (aslot) * 2048; \
    const short*    pb = ldsB + (bslot) * 4096; \
    short8 af[4], bf[4]; \
    _Pragma("unroll") \
    for (int i = 0; i < 4; ++i) { \
      union { unsigned u[4]; short8 s; } av_; \
      av_.u[0] = pa[abase[i]]; \
      av_.u[1] = pa[(abase[i] ^ 4) + 128]; \
      av_.u[2] = pa[abase[i] + 256]; \
      av_.u[3] = pa[(abase[i] ^ 4) + 384]; \
      af[i] = av_.s; \
    } \
    _Pragma("unroll") \
    for (int j = 0; j < 4; ++j) bf[j] = *(const short8*)(pb + boff[j]); \
    __builtin_amdgcn_s_setprio(1); \
    _Pragma("unroll") \
    for (int i = 0; i < 4; ++i) \
      _Pragma("unroll") \
      for (int j = 0; j < 4; ++j) \
        acc[i][j] = __builtin_amdgcn_mfma_f32_16x16x32_bf16(af[i], bf[j], acc[i][j], 0, 0, 0); \
    __builtin_amdgcn_s_setprio(0); \
  } while (0)

  // ---- prologue: B tiles 0,1; A(0)->aX, A(1)->aY
  ISSUE_B(0, 0);
  ISSUE_B(1, 1);
  ISSUE_A(aX, 0);
  ISSUE_A(aY, 1);
  WAITVM(4);                 // retires B0,B1,aX(0); aY(1) in flight
  WRITE_A(0, aX);

  // ---- t = 0
  ISSUE_A(aX, 2);
  WAITVM(4); LGKM0();        // retires aY(1); aX(2) in flight
  FULL_BAR();
  ISSUE_B(2, 2);
  WRITE_A(1, aY);
  COMPUTE(0, 0);

  // ---- t = 1..12 (6 pairs)
  for (int k = 0; k < 6; ++k) {
    const int t = 2 * k + 1;                   // odd: 1,3,5,7,9,11
    ISSUE_A(aY, t + 2);
    WAITVM(6); LGKM0();                        // retires aX(t+1) + B(t)
    FULL_BAR();
    ISSUE_B((t + 2) % 3, t + 2);               // post-barrier: race-free
    WRITE_A(0, aX);
    COMPUTE(1, t % 3);
    // even t+1
    ISSUE_A(aX, t + 3);
    WAITVM(6); LGKM0();                        // retires aY(t+2) + B(t+1)
    FULL_BAR();
    ISSUE_B((t + 3) % 3, t + 3);
    WRITE_A(1, aY);
    COMPUTE(0, (t + 1) % 3);
  }

  // ---- t = 13
  ISSUE_A(aY, 15);
  WAITVM(6); LGKM0();        // retires aX(14) + B(13)
  FULL_BAR();
  ISSUE_B(0, 15);            // 15 % 3 = 0
  WRITE_A(0, aX);
  COMPUTE(1, 1);             // 13 % 3
  // ---- t = 14
  WAITVM(2); LGKM0();        // retires aY(15) + B(14)
  FULL_BAR();
  WRITE_A(1, aY);
  COMPUTE(0, 2);             // 14 % 3
  // ---- t = 15
  WAITVM(0); LGKM0();        // retires B(15)
  FULL_BAR();
  COMPUTE(1, 0);             // 15 % 3

#undef ISSUE_A
#undef ISSUE_B
#undef WRITE_A
#undef COMPUTE

  // epilogue: bias + bf16, scatter into window-token layout
  float bj[4];
#pragma unroll
  for (int j = 0; j < 4; ++j) bj[j] = bias[e0 + wn * 64 + j * 16 + lr];
#pragma unroll
  for (int i = 0; i < 4; ++i) {
#pragma unroll
    for (int r = 0; r < 4; ++r) {
      const int token = tok0 + wm * 64 + i * 16 + lg * 4 + r;
      const int hw = token & (HW - 1);
      const int h = hw >> 6, w = hw & 63;
      const int nwin = ((token >> 12) << 6) + ((h >> 3) << 3) + (w >> 3);
      const int twin = ((h & 7) << 3) + (w & 7);
      short* orow = O + ((size_t)(nwin * 64 + twin) << 9) + e0 + wn * 64 + lr;
#pragma unroll
      for (int j = 0; j < 4; ++j)
        orow[j * 16] = f2bf(acc[i][j][r] + bj[j]);
    }
  }
}

// ---------------------------------------------------------------------------
// attn: one block (4 waves) per (head, window)
// ---------------------------------------------------------------------------
__global__ __launch_bounds__(256) void attn_kernel(
    const short* __restrict__ Qp, const short* __restrict__ Kp,
    const short* __restrict__ Vp, short* __restrict__ Ob)
{
  const int head = blockIdx.x, nwin = blockIdx.y;
  const int base = nwin * (64 * E_DIM) + head * 64;

  __shared__ short lQ[64 * 64];
  __shared__ short lK[64 * 64];
  __shared__ short lVT[64 * 64];

  const int tid = threadIdx.x;
  {
    const int row = tid >> 2, sg = (tid & 3) * 16;
    const int go = base + row * E_DIM + sg;
    *(short8*)&lQ[swzidx(row, sg)]     = *(const short8*)&Qp[go];
    *(short8*)&lQ[swzidx(row, sg + 8)] = *(const short8*)&Qp[go + 8];
    *(short8*)&lK[swzidx(row, sg)]     = *(const short8*)&Kp[go];
    *(short8*)&lK[swzidx(row, sg + 8)] = *(const short8*)&Kp[go + 8];
    const int tv = tid & 63, d0 = (tid >> 6) * 16;
    const int gv = base + tv * E_DIM + d0;
    short8 v0 = *(const short8*)&Vp[gv];
    short8 v1 = *(const short8*)&Vp[gv + 8];
#pragma unroll
    for (int ii = 0; ii < 8; ++ii) lVT[swzidx(d0 + ii, tv)] = v0[ii];
#pragma unroll
    for (int ii = 0; ii < 8; ++ii) lVT[swzidx(d0 + 8 + ii, tv)] = v1[ii];
  }
  __syncthreads();

  const int lane = tid & 63, wv = tid >> 6;
  const int lr = lane & 15, lg = lane >> 4;
  const int m0 = wv * 16;

  f32x4 s[4];
#pragma unroll
  for (int j = 0; j < 4; ++j) s[j] = (f32x4){0.f, 0.f, 0.f, 0.f};
#pragma unroll
  for (int ks = 0; ks < 2; ++ks) {
    const int kk = ks * 32 + lg * 8;
    short8 a = *(const short8*)&lQ[swzidx(m0 + lr, kk)];
#pragma unroll
    for (int j = 0; j < 4; ++j) {
      short8 b = *(const short8*)&lK[swzidx(j * 16 + lr, kk)];
      s[j] = __builtin_amdgcn_mfma_f32_16x16x32_bf16(a, b, s[j], 0, 0, 0);
    }
  }

  const float cexp = 0.125f * 1.4426950408889634f;
  float p[4][4], rs[4];
#pragma unroll
  for (int r = 0; r < 4; ++r) {
    float mx = fmaxf(fmaxf(s[0][r], s[1][r]), fmaxf(s[2][r], s[3][r]));
    mx = fmaxf(mx, __shfl_xor(mx, 1));
    mx = fmaxf(mx, __shfl_xor(mx, 2));
    mx = fmaxf(mx, __shfl_xor(mx, 4));
    mx = fmaxf(mx, __shfl_xor(mx, 8));
    float sm = 0.f;
#pragma unroll
    for (int j = 0; j < 4; ++j) { p[j][r] = exp2f((s[j][r] - mx) * cexp); sm += p[j][r]; }
    sm += __shfl_xor(sm, 1); sm += __shfl_xor(sm, 2);
    sm += __shfl_xor(sm, 4); sm += __shfl_xor(sm, 8);
    rs[r] = 1.0f / sm;
  }

#pragma unroll
  for (int r = 0; r < 4; ++r)
#pragma unroll
    for (int j = 0; j < 4; ++j)
      lQ[swzidx(m0 + lg * 4 + r, j * 16 + lr)] = f2bf(p[j][r]);

  f32x4 o[4];
#pragma unroll
  for (int nf = 0; nf < 4; ++nf) o[nf] = (f32x4){0.f, 0.f, 0.f, 0.f};
#pragma unroll
  for (int ks = 0; ks < 2; ++ks) {
    const int kk = ks * 32 + lg * 8;
    short8 a = *(const short8*)&lQ[swzidx(m0 + lr, kk)];
#pragma unroll
    for (int nf = 0; nf < 4; ++nf) {
      short8 b = *(const short8*)&lVT[swzidx(nf * 16 + lr, kk)];
      o[nf] = __builtin_amdgcn_mfma_f32_16x16x32_bf16(a, b, o[nf], 0, 0, 0);
    }
  }

#pragma unroll
  for (int r = 0; r < 4; ++r) {
    const int t = m0 + lg * 4 + r;
    short* orow = Ob + base + t * E_DIM + lr;
#pragma unroll
    for (int nf = 0; nf < 4; ++nf)
      orow[nf * 16] = f2bf(o[nf][r] * rs[r]);
  }
}

// ---------------------------------------------------------------------------
// oproj: C[e, tok] = Wo[e,:] . o[tok,:] + bo[e]; 4-slot gload_lds ring
// ---------------------------------------------------------------------------
__global__ __launch_bounds__(512, 2) void oproj_kernel(
    const short* __restrict__ Ob, const float* __restrict__ bo,
    float* __restrict__ Out)
{
  const int wg  = blockIdx.x;                 // 256 = 8 * 32
  const int swz = (wg & 7) * 32 + (wg >> 3);
  const int e0 = (swz & 1) << 8, tok0 = (swz >> 1) << 8;
  const short* Wo = g_wbf + 1536 * E_DIM;

  __shared__ short lds[4 * 16384];

  const int tid = threadIdx.x, lane = tid & 63, wv = tid >> 6;
  const int wm = wv >> 2, wn = wv & 3;
  const int lr = lane & 15, lg = lane >> 4;

  int r0, k0c, r1, k1c;
  chunk_map(tid, r0, k0c);
  chunk_map(512 + tid, r1, k1c);
  const short* sA0 = Wo + (size_t)(e0 + r0) * E_DIM + k0c * 8;
  const short* sA1 = Wo + (size_t)(e0 + r1) * E_DIM + k1c * 8;
  const short* sB0 = Ob + (size_t)(tok0 + r0) * E_DIM + k0c * 8;
  const short* sB1 = Ob + (size_t)(tok0 + r1) * E_DIM + k1c * 8;
  const int dc0 = (wv * 64) * 8, dc1 = (512 + wv * 64) * 8;

  int aoff[8], boff[4];
#pragma unroll
  for (int i = 0; i < 8; ++i) aoff[i] = tile_off(wm * 128 + i * 16 + lr, lg);
#pragma unroll
  for (int j = 0; j < 4; ++j) boff[j] = 8192 + tile_off(wn * 64 + j * 16 + lr, lg);

  f32x4 acc[8][4];
#pragma unroll
  for (int i = 0; i < 8; ++i)
#pragma unroll
    for (int j = 0; j < 4; ++j) acc[i][j] = (f32x4){0.f, 0.f, 0.f, 0.f};

  auto STAGE = [&](int slot, int kt) {
    const int sb = slot * 16384, ko = kt * 32;
    GLOAD16(sA0 + ko, &lds[sb + dc0]);
    GLOAD16(sA1 + ko, &lds[sb + dc1]);
    GLOAD16(sB0 + ko, &lds[sb + 8192 + dc0]);
    GLOAD16(sB1 + ko, &lds[sb + 8192 + dc1]);
  };
  auto COMPUTE = [&](int slot) {
    const int sb = slot * 16384;
    short8 af[8], bf[4];
#pragma unroll
    for (int i = 0; i < 8; ++i) af[i] = *(const short8*)&lds[sb + aoff[i]];
#pragma unroll
    for (int j = 0; j < 4; ++j) bf[j] = *(const short8*)&lds[sb + boff[j]];
    __builtin_amdgcn_s_setprio(1);
#pragma unroll
    for (int i = 0; i < 8; ++i)
#pragma unroll
      for (int j = 0; j < 4; ++j)
        acc[i][j] = __builtin_amdgcn_mfma_f32_16x16x32_bf16(af[i], bf[j], acc[i][j], 0, 0, 0);
    __builtin_amdgcn_s_setprio(0);
  };

  STAGE(0, 0); STAGE(1, 1); STAGE(2, 2);
  for (int t = 0; t < 13; ++t) {
    WAITVM(8);
    FULL_BAR();
    STAGE((t + 3) & 3, t + 3);
    COMPUTE(t & 3);
  }
  WAITVM(8); FULL_BAR(); COMPUTE(13 & 3);
  WAITVM(4); FULL_BAR(); COMPUTE(14 & 3);
  WAITVM(0); FULL_BAR(); COMPUTE(15 & 3);

#pragma unroll
  for (int i = 0; i < 8; ++i) {
#pragma unroll
    for (int r = 0; r < 4; ++r) {
      const int e = e0 + wm * 128 + i * 16 + lg * 4 + r;
      const float be = bo[e];
#pragma unroll
      for (int j = 0; j < 4; ++j) {
        const int wtok = tok0 + wn * 64 + j * 16 + lr;
        const int n = wtok >> 6, t = wtok & 63;
        const int b = n >> 6;
        const int h = (((n >> 3) & 7) << 3) + (t >> 3);
        const int w = ((n & 7) << 3) + (t & 7);
        Out[(size_t)b * (E_DIM * HW) + (size_t)e * HW + (h << 6) + w] =
            acc[i][j][r] + be;
      }
    }
  }
}

// ---------------------------------------------------------------------------
extern "C" void kernel_launch(void* const* d_in, const int* in_sizes, int n_in,
                              void* d_out, int out_size, void* d_ws, size_t ws_size,
                              hipStream_t stream) {
  const float* q     = (const float*)d_in[0];
  const float* k     = (const float*)d_in[1];
  const float* v     = (const float*)d_in[2];
  const float* in_w  = (const float*)d_in[3];
  const float* in_b  = (const float*)d_in[4];
  const float* out_w = (const float*)d_in[5];
  const float* out_b = (const float*)d_in[6];
  float* out = (float*)d_out;

  // d_ws: qp @0, kp @32Mi, vp @64Mi, ob @96Mi (4 x 32 MiB bf16)
  short* qp = (short*)d_ws;
  short* kp = qp + NTE;
  short* vp = kp + NTE;
  short* ob = vp + NTE;

  convert_w<<<512, 256, 0, stream>>>(in_w, out_w);
  proj_kernel<<<3072, 256, 0, stream>>>(q, k, v, in_b, qp, kp, vp);
  attn_kernel<<<dim3(8, 512), 256, 0, stream>>>(qp, kp, vp, ob);
  oproj_kernel<<<256, 512, 0, stream>>>(ob, out_b, out);
}

// Round 16
// 196.535 us; speedup vs baseline: 1.0214x; 1.0214x over previous
//
#include <hip/hip_runtime.h>

typedef __attribute__((ext_vector_type(4))) float f32x4;
typedef __attribute__((ext_vector_type(8))) short short8;
typedef __attribute__((ext_vector_type(4))) unsigned uint4v;

#define E_DIM 512
#define HW    4096      // 64*64 spatial per batch
#define NT    32768     // total tokens
#define NTE   16777216  // NT*E_DIM elements (32 MiB as bf16)

// bf16 copies of in_proj_w (rows 0..1535) and out_proj_w (rows 1536..2047)
__device__ short g_wbf[2048 * E_DIM];

// round-to-nearest-even f32 -> bf16 bits
__device__ __forceinline__ short f2bf(float f) {
  union { float f; unsigned u; } v; v.f = f;
  unsigned u = v.u;
  u += 0x7fffu + ((u >> 16) & 1u);
  return (short)(u >> 16);
}
__device__ __forceinline__ unsigned pack_bf2(float lo, float hi) {
  return (unsigned)(unsigned short)f2bf(lo) | ((unsigned)(unsigned short)f2bf(hi) << 16);
}

// ---- staged bf16 tile (gload_lds): 128B lines = 2 rows x 4 chunks,
// physical chunk = logical ^ (line&7)  -> 2-way (free) ds_read_b128 banks
__device__ __forceinline__ void chunk_map(int c, int& row, int& kc) {
  const int line = c >> 3;
  const int l = (c & 7) ^ (line & 7);
  row = line * 2 + (l >> 2);
  kc = l & 3;
}
__device__ __forceinline__ int tile_off(int row, int kc) {  // in shorts
  const int line = row >> 1;
  const int phys = (((row & 1) << 2) | kc) ^ (line & 7);
  return line * 64 + phys * 8;
}

// async global->LDS, 16B per lane; LDS dest = wave-uniform base (+lane*16 HW)
#define GLOAD16(g, l) __builtin_amdgcn_global_load_lds( \
    (const __attribute__((address_space(1))) void*)(g), \
    (__attribute__((address_space(3))) void*)(l), 16, 0, 0)

#define WAITVM(N) asm volatile("s_waitcnt vmcnt(" #N ")" ::: "memory")
#define LGKM0()   asm volatile("s_waitcnt lgkmcnt(0)" ::: "memory")
#define FULL_BAR() do { asm volatile("" ::: "memory"); \
  __builtin_amdgcn_s_barrier(); asm volatile("" ::: "memory"); } while (0)

// ---------------------------------------------------------------------------
// convert_w: f32 -> bf16 for both weight matrices into g_wbf
// ---------------------------------------------------------------------------
__global__ __launch_bounds__(256) void convert_w(
    const float* __restrict__ w_in, const float* __restrict__ w_out)
{
  const size_t off = ((size_t)blockIdx.x * 256 + threadIdx.x) * 8;
  const float* src = (off < 786432) ? (w_in + off) : (w_out + (off - 786432));
  f32x4 a = *(const f32x4*)src, b = *(const f32x4*)(src + 4);
  short8 s;
#pragma unroll
  for (int j = 0; j < 4; ++j) { s[j] = f2bf(a[j]); s[4 + j] = f2bf(b[j]); }
  *(short8*)&g_wbf[off] = s;
}

// ---------------------------------------------------------------------------
// proj: R9-exact best-known (107us). 256x256 tile, BK=32, 8 waves.
// A: global->reg f32 depth-2 -> pack bf16 -> LDS [fp][tok], 2 slots.
// B: global_load_lds, 3-slot ring, issue-after-barrier 2 tiles ahead.
// Plateau notes: occupancy capped by acc[8][4]=128 regs (1 block/CU); all
// schedule variants (R10/R13/R14/R15) landed 107-155 -> frozen.
// ---------------------------------------------------------------------------
__global__ __launch_bounds__(512, 2) void proj_kernel(
    const float* __restrict__ Xq, const float* __restrict__ Xk,
    const float* __restrict__ Xv, const float* __restrict__ Bfull,
    short* __restrict__ Oq, short* __restrict__ Ok, short* __restrict__ Ov)
{
  const int wg  = blockIdx.x;
  const int swz = (wg & 7) * 96 + (wg >> 3);
  const int z = swz >> 8, rr = swz & 255;
  const int e0 = (rr & 1) << 8, tok0 = (rr >> 1) << 8;

  const float* X  = (z == 0) ? Xq : (z == 1) ? Xk : Xv;
  const short* Wz = g_wbf + z * (E_DIM * E_DIM);
  const float* bias = Bfull + z * E_DIM;
  short* O = (z == 0) ? Oq : (z == 1) ? Ok : Ov;

  const int b   = tok0 >> 12;
  const int hw0 = tok0 & (HW - 1);
  const float* Xb = X + (size_t)b * E_DIM * HW + hw0;

  __shared__ unsigned ldsA[2 * 4096];   // 2 slots: [16 fp][256 tok] u32
  __shared__ short    ldsB[3 * 8192];   // 3 slots: 256x32 bf16, tile_off swz

  const int tid = threadIdx.x, lane = tid & 63, wv = tid >> 6;
  const int wm = wv >> 2, wn = wv & 3;
  const int lr = lane & 15, lg = lane >> 4;

  const int fp = tid >> 5;
  const int hw8 = (tid & 31) * 8;
  const float* arow0 = Xb + (size_t)(2 * fp) * HW + hw8;
  const int keyw = (fp >> 3) << 4;
  const int aWbase = fp * 256 + (hw8 ^ keyw);

  int r0, k0c, r1, k1c;
  chunk_map(tid, r0, k0c);
  chunk_map(512 + tid, r1, k1c);
  const short* sB0 = Wz + (size_t)(e0 + r0) * E_DIM + k0c * 8;
  const short* sB1 = Wz + (size_t)(e0 + r1) * E_DIM + k1c * 8;
  const int dc0 = (wv * 64) * 8, dc1 = (512 + wv * 64) * 8;

  const int keyr = (lg >> 1) << 4;
  int aoff[8], boff[4];
#pragma unroll
  for (int i = 0; i < 8; ++i)
    aoff[i] = lg * 1024 + ((wm * 128 + i * 16 + lr) ^ keyr);
#pragma unroll
  for (int j = 0; j < 4; ++j) boff[j] = tile_off(wn * 64 + j * 16 + lr, lg);

  f32x4 acc[8][4];
#pragma unroll
  for (int i = 0; i < 8; ++i)
#pragma unroll
    for (int j = 0; j < 4; ++j) acc[i][j] = (f32x4){0.f, 0.f, 0.f, 0.f};

  f32x4 aX[4], aY[4];

#define ISSUE_A(dst, kt) do { \
    const float* ap = arow0 + (size_t)(kt) * (32 * HW); \
    dst[0] = *(const f32x4*)(ap);          dst[1] = *(const f32x4*)(ap + 4); \
    dst[2] = *(const f32x4*)(ap + HW);     dst[3] = *(const f32x4*)(ap + 4 + HW); \
  } while (0)

#define ISSUE_B(slot, kt) do { \
    const int ko2 = (kt) * 32, sb2 = (slot) * 8192; \
    GLOAD16(sB0 + ko2, &ldsB[sb2 + dc0]); \
    GLOAD16(sB1 + ko2, &ldsB[sb2 + dc1]); \
  } while (0)

#define WRITE_A(slot, src) do { \
    unsigned* dA = &ldsA[(slot) * 4096 + aWbase]; \
    uint4v lo_, hi_; \
    _Pragma("unroll") \
    for (int j = 0; j < 4; ++j) { \
      lo_[j] = pack_bf2(src[0][j], src[2][j]); \
      hi_[j] = pack_bf2(src[1][j], src[3][j]); \
    } \
    *(uint4v*)(dA) = lo_; \
    *(uint4v*)(dA + 4) = hi_; \
  } while (0)

#define COMPUTE(aslot, bslot) do { \
    const unsigned* pa = ldsA + (aslot) * 4096; \
    const short*    pb = ldsB + (bslot) * 8192; \
    short8 af[8], bf[4]; \
    _Pragma("unroll") \
    for (int i = 0; i < 8; ++i) { \
      union { unsigned u[4]; short8 s; } av_; \
      av_.u[0] = pa[aoff[i]];       av_.u[1] = pa[aoff[i] + 256]; \
      av_.u[2] = pa[aoff[i] + 512]; av_.u[3] = pa[aoff[i] + 768]; \
      af[i] = av_.s; \
    } \
    _Pragma("unroll") \
    for (int j = 0; j < 4; ++j) bf[j] = *(const short8*)(pb + boff[j]); \
    __builtin_amdgcn_s_setprio(1); \
    _Pragma("unroll") \
    for (int i = 0; i < 8; ++i) \
      _Pragma("unroll") \
      for (int j = 0; j < 4; ++j) \
        acc[i][j] = __builtin_amdgcn_mfma_f32_16x16x32_bf16(af[i], bf[j], acc[i][j], 0, 0, 0); \
    __builtin_amdgcn_s_setprio(0); \
  } while (0)

  ISSUE_B(0, 0);
  ISSUE_B(1, 1);
  ISSUE_A(aX, 0);
  ISSUE_A(aY, 1);
  WAITVM(4);
  WRITE_A(0, aX);

  ISSUE_A(aX, 2);
  WAITVM(4); LGKM0();
  FULL_BAR();
  ISSUE_B(2, 2);
  WRITE_A(1, aY);
  COMPUTE(0, 0);

  for (int k = 0; k < 6; ++k) {
    const int t = 2 * k + 1;
    ISSUE_A(aY, t + 2);
    WAITVM(6); LGKM0();
    FULL_BAR();
    ISSUE_B((t + 2) % 3, t + 2);
    WRITE_A(0, aX);
    COMPUTE(1, t % 3);
    ISSUE_A(aX, t + 3);
    WAITVM(6); LGKM0();
    FULL_BAR();
    ISSUE_B((t + 3) % 3, t + 3);
    WRITE_A(1, aY);
    COMPUTE(0, (t + 1) % 3);
  }

  ISSUE_A(aY, 15);
  WAITVM(6); LGKM0();
  FULL_BAR();
  ISSUE_B(0, 15);
  WRITE_A(0, aX);
  COMPUTE(1, 1);
  WAITVM(2); LGKM0();
  FULL_BAR();
  WRITE_A(1, aY);
  COMPUTE(0, 2);
  WAITVM(0); LGKM0();
  FULL_BAR();
  COMPUTE(1, 0);

#undef ISSUE_A
#undef ISSUE_B
#undef WRITE_A
#undef COMPUTE

  float bj[4];
#pragma unroll
  for (int j = 0; j < 4; ++j) bj[j] = bias[e0 + wn * 64 + j * 16 + lr];
#pragma unroll
  for (int i = 0; i < 8; ++i) {
#pragma unroll
    for (int r = 0; r < 4; ++r) {
      const int token = tok0 + wm * 128 + i * 16 + lg * 4 + r;
      const int hw = token & (HW - 1);
      const int h = hw >> 6, w = hw & 63;
      const int nwin = ((token >> 12) << 6) + ((h >> 3) << 3) + (w >> 3);
      const int twin = ((h & 7) << 3) + (w & 7);
      short* orow = O + ((size_t)(nwin * 64 + twin) << 9) + e0 + wn * 64 + lr;
#pragma unroll
      for (int j = 0; j < 4; ++j)
        orow[j * 16] = f2bf(acc[i][j][r] + bj[j]);
    }
  }
}

// ---------------------------------------------------------------------------
// attn_oproj: fused attention + output projection. Block = 1 window, 8 waves;
// wave h = head h. Eliminates the ob global round trip (64 MB) + one launch.
// Phase A (per wave, no barriers): Q,K direct global->frags (64B-granule via
//   lg-quad); V^T staged in per-head LDS (double-XOR swizzle, 2-way banks);
//   QK^T -> wave-parallel softmax -> P in per-head LDS -> PV.
// barrier; O (x 1/l) -> R1 as [64 tok][512 e] chunk-swizzled; barrier.
// Phase B (no barriers): wave h computes out rows e=[64h,64h+64):
//   C^T = Wo . O^T, Wo direct from L2, O from LDS (2-way reads);
//   epilogue = w-contiguous unpartition scatter + bias (proven oproj pattern).
// ---------------------------------------------------------------------------
__global__ __launch_bounds__(512) void attn_oproj(
    const short* __restrict__ Qp, const short* __restrict__ Kp,
    const short* __restrict__ Vp, const float* __restrict__ bo,
    float* __restrict__ Out)
{
  const int nwin = blockIdx.x;
  const int tid = threadIdx.x, lane = tid & 63, h = tid >> 6;
  const int lr = lane & 15, lg = lane >> 4;
  const size_t base = (size_t)nwin * (64 * E_DIM) + h * 64;

  __shared__ short R1[64 * 512];   // per-head P (8KB each) -> then O[64][512]
  __shared__ short R2[64 * 512];   // per-head V^T (8KB each)
  short* P  = R1 + h * 4096;       // [tok][ktok] swizzled
  short* VT = R2 + h * 4096;       // [d][tok] double-XOR swizzled

  // ---- Q frags direct from global (lanes {l,l+16,l+32,l+48} = 64B runs)
  short8 q8[4][2];
#pragma unroll
  for (int i = 0; i < 4; ++i)
#pragma unroll
    for (int ks = 0; ks < 2; ++ks)
      q8[i][ks] = *(const short8*)&Qp[base + (size_t)(i * 16 + lr) * E_DIM + ks * 32 + lg * 8];

  // ---- stage V^T: lane reads V[row][vc*8..+8] (128B-contiguous per octet),
  // writes 8 scalars; chunk ^= (d&7)^(d>>3) -> 2-way banks both sides
  {
    const int vr = lane >> 3, vc = lane & 7;
#pragma unroll
    for (int r8 = 0; r8 < 8; ++r8) {
      const int row = r8 * 8 + vr;
      short8 v8 = *(const short8*)&Vp[base + (size_t)row * E_DIM + vc * 8];
#pragma unroll
      for (int ii = 0; ii < 8; ++ii) {
        const int d = vc * 8 + ii;
        VT[d * 64 + (row ^ ((((d & 7) ^ (d >> 3)) & 7) << 3))] = v8[ii];
      }
    }
  }

  // ---- S = Q K^T (K loaded per-j to cap registers)
  f32x4 s[4][4];
#pragma unroll
  for (int i = 0; i < 4; ++i)
#pragma unroll
    for (int j = 0; j < 4; ++j) s[i][j] = (f32x4){0.f, 0.f, 0.f, 0.f};
#pragma unroll
  for (int ks = 0; ks < 2; ++ks)
#pragma unroll
    for (int j = 0; j < 4; ++j) {
      short8 k8 = *(const short8*)&Kp[base + (size_t)(j * 16 + lr) * E_DIM + ks * 32 + lg * 8];
#pragma unroll
      for (int i = 0; i < 4; ++i)
        s[i][j] = __builtin_amdgcn_mfma_f32_16x16x32_bf16(q8[i][ks], k8, s[i][j], 0, 0, 0);
    }

  // ---- softmax (scale 1/8 folded into exp2) + P -> LDS (unnormalized)
  const float cexp = 0.125f * 1.4426950408889634f;
  float rs[4][4];
#pragma unroll
  for (int i = 0; i < 4; ++i)
#pragma unroll
    for (int r = 0; r < 4; ++r) {
      float mx = fmaxf(fmaxf(s[i][0][r], s[i][1][r]), fmaxf(s[i][2][r], s[i][3][r]));
      mx = fmaxf(mx, __shfl_xor(mx, 1));
      mx = fmaxf(mx, __shfl_xor(mx, 2));
      mx = fmaxf(mx, __shfl_xor(mx, 4));
      mx = fmaxf(mx, __shfl_xor(mx, 8));
      float p[4], sm = 0.f;
#pragma unroll
      for (int j = 0; j < 4; ++j) { p[j] = exp2f((s[i][j][r] - mx) * cexp); sm += p[j]; }
      sm += __shfl_xor(sm, 1); sm += __shfl_xor(sm, 2);
      sm += __shfl_xor(sm, 4); sm += __shfl_xor(sm, 8);
      rs[i][r] = 1.0f / sm;
      const int t = i * 16 + lg * 4 + r;
#pragma unroll
      for (int j = 0; j < 4; ++j)
        P[t * 64 + ((j * 16 + lr) ^ ((t & 7) << 3))] = f2bf(p[j]);
    }

  // ---- O = P V  (all LDS same-wave; compiler inserts lgkm waits)
  f32x4 o[4][4];
#pragma unroll
  for (int i = 0; i < 4; ++i)
#pragma unroll
    for (int nf = 0; nf < 4; ++nf) o[i][nf] = (f32x4){0.f, 0.f, 0.f, 0.f};
#pragma unroll
  for (int ks = 0; ks < 2; ++ks) {
    short8 vt8[4];
#pragma unroll
    for (int nf = 0; nf < 4; ++nf) {
      const int d = nf * 16 + lr;
      vt8[nf] = *(const short8*)&VT[d * 64 + ((ks * 32 + lg * 8) ^ ((((d & 7) ^ (d >> 3)) & 7) << 3))];
    }
#pragma unroll
    for (int i = 0; i < 4; ++i) {
      const int t = i * 16 + lr;
      short8 pa8 = *(const short8*)&P[t * 64 + ((ks * 32 + lg * 8) ^ ((t & 7) << 3))];
#pragma unroll
      for (int nf = 0; nf < 4; ++nf)
        o[i][nf] = __builtin_amdgcn_mfma_f32_16x16x32_bf16(pa8, vt8[nf], o[i][nf], 0, 0, 0);
    }
  }

  __syncthreads();   // all P/VT reads done before R1 is overlaid with O

  // ---- O (normalized, bf16) -> R1 as [64 tok][512 e], chunk ^= (tok&7)
#pragma unroll
  for (int i = 0; i < 4; ++i)
#pragma unroll
    for (int r = 0; r < 4; ++r) {
      const int t = i * 16 + lg * 4 + r;
      const int swzk = (t & 7) << 3;
#pragma unroll
      for (int nf = 0; nf < 4; ++nf)
        R1[t * 512 + ((h * 64 + nf * 16 + lr) ^ swzk)] = f2bf(o[i][nf][r] * rs[i][r]);
    }

  __syncthreads();   // O complete before phase B reads

  // ---- Phase B: out rows e = [64h, 64h+64), C^T = Wo . O^T, K=512
  const short* Wo = g_wbf + 1536 * E_DIM;
  const int E0 = h * 64;
  f32x4 o2[4][4];
#pragma unroll
  for (int mi = 0; mi < 4; ++mi)
#pragma unroll
    for (int nj = 0; nj < 4; ++nj) o2[mi][nj] = (f32x4){0.f, 0.f, 0.f, 0.f};

#pragma unroll 2
  for (int k0 = 0; k0 < E_DIM; k0 += 32) {
    short8 wa[4], ob8[4];
#pragma unroll
    for (int mi = 0; mi < 4; ++mi)
      wa[mi] = *(const short8*)&Wo[(size_t)(E0 + mi * 16 + lr) * E_DIM + k0 + lg * 8];
#pragma unroll
    for (int nj = 0; nj < 4; ++nj) {
      const int t = nj * 16 + lr;
      ob8[nj] = *(const short8*)&R1[t * 512 + ((k0 + lg * 8) ^ ((t & 7) << 3))];
    }
#pragma unroll
    for (int mi = 0; mi < 4; ++mi)
#pragma unroll
      for (int nj = 0; nj < 4; ++nj)
        o2[mi][nj] = __builtin_amdgcn_mfma_f32_16x16x32_bf16(wa[mi], ob8[nj], o2[mi][nj], 0, 0, 0);
  }

  // ---- epilogue: unpartition, bias, f32 store (w-contiguous segments)
  const int bb = nwin >> 6;
  const int wh0 = ((nwin >> 3) & 7) << 3, ww0 = (nwin & 7) << 3;
  float* outb = Out + (size_t)bb * (E_DIM * HW);
#pragma unroll
  for (int mi = 0; mi < 4; ++mi)
#pragma unroll
    for (int r = 0; r < 4; ++r) {
      const int e = E0 + mi * 16 + lg * 4 + r;
      const float be = bo[e];
#pragma unroll
      for (int nj = 0; nj < 4; ++nj) {
        const int t = nj * 16 + lr;
        outb[(size_t)e * HW + (wh0 + (t >> 3)) * 64 + ww0 + (t & 7)] =
            o2[mi][nj][r] + be;
      }
    }
}

// ---------------------------------------------------------------------------
extern "C" void kernel_launch(void* const* d_in, const int* in_sizes, int n_in,
                              void* d_out, int out_size, void* d_ws, size_t ws_size,
                              hipStream_t stream) {
  const float* q     = (const float*)d_in[0];
  const float* k     = (const float*)d_in[1];
  const float* v     = (const float*)d_in[2];
  const float* in_w  = (const float*)d_in[3];
  const float* in_b  = (const float*)d_in[4];
  const float* out_w = (const float*)d_in[5];
  const float* out_b = (const float*)d_in[6];
  float* out = (float*)d_out;

  // d_ws: qp @0, kp @32Mi, vp @64Mi (3 x 32 MiB bf16)
  short* qp = (short*)d_ws;
  short* kp = qp + NTE;
  short* vp = kp + NTE;

  convert_w<<<512, 256, 0, stream>>>(in_w, out_w);
  proj_kernel<<<768, 512, 0, stream>>>(q, k, v, in_b, qp, kp, vp);
  attn_oproj<<<512, 512, 0, stream>>>(qp, kp, vp, out_b, out);
}

// Round 17
// 184.626 us; speedup vs baseline: 1.0872x; 1.0645x over previous
//
#include <hip/hip_runtime.h>

typedef __attribute__((ext_vector_type(4))) float f32x4;
typedef __attribute__((ext_vector_type(8))) short short8;
typedef __attribute__((ext_vector_type(4))) unsigned uint4v;

#define E_DIM 512
#define HW    4096      // 64*64 spatial per batch
#define NT    32768     // total tokens
#define NTE   16777216  // NT*E_DIM elements (32 MiB as bf16)

// bf16 copies of in_proj_w (rows 0..1535) and out_proj_w (rows 1536..2047)
__device__ short g_wbf[2048 * E_DIM];

// round-to-nearest-even f32 -> bf16 bits
__device__ __forceinline__ short f2bf(float f) {
  union { float f; unsigned u; } v; v.f = f;
  unsigned u = v.u;
  u += 0x7fffu + ((u >> 16) & 1u);
  return (short)(u >> 16);
}
__device__ __forceinline__ unsigned pack_bf2(float lo, float hi) {
  return (unsigned)(unsigned short)f2bf(lo) | ((unsigned)(unsigned short)f2bf(hi) << 16);
}

// attn-kernel swizzle: [rows][64] bf16 tile, chunk ^= (row&7)
__device__ __forceinline__ int swzidx(int row, int k) {
  return row * 64 + (k ^ ((row & 7) << 3));
}

// ---- 256x32 bf16 staged tile (gload_lds): 128B lines = 2 rows x 4 chunks,
// physical chunk = logical ^ (line&7)  -> 2-way (free) ds_read_b128 banks
__device__ __forceinline__ void chunk_map(int c, int& row, int& kc) {
  const int line = c >> 3;
  const int l = (c & 7) ^ (line & 7);
  row = line * 2 + (l >> 2);
  kc = l & 3;
}
__device__ __forceinline__ int tile_off(int row, int kc) {  // in shorts
  const int line = row >> 1;
  const int phys = (((row & 1) << 2) | kc) ^ (line & 7);
  return line * 64 + phys * 8;
}

// async global->LDS, 16B per lane; LDS dest = wave-uniform base (+lane*16 HW)
#define GLOAD16(g, l) __builtin_amdgcn_global_load_lds( \
    (const __attribute__((address_space(1))) void*)(g), \
    (__attribute__((address_space(3))) void*)(l), 16, 0, 0)

#define WAITVM(N) asm volatile("s_waitcnt vmcnt(" #N ")" ::: "memory")
#define LGKM0()   asm volatile("s_waitcnt lgkmcnt(0)" ::: "memory")
#define FULL_BAR() do { asm volatile("" ::: "memory"); \
  __builtin_amdgcn_s_barrier(); asm volatile("" ::: "memory"); } while (0)

// ---------------------------------------------------------------------------
// convert_w: f32 -> bf16 for both weight matrices into g_wbf
// ---------------------------------------------------------------------------
__global__ __launch_bounds__(256) void convert_w(
    const float* __restrict__ w_in, const float* __restrict__ w_out)
{
  const size_t off = ((size_t)blockIdx.x * 256 + threadIdx.x) * 8;
  const float* src = (off < 786432) ? (w_in + off) : (w_out + (off - 786432));
  f32x4 a = *(const f32x4*)src, b = *(const f32x4*)(src + 4);
  short8 s;
#pragma unroll
  for (int j = 0; j < 4; ++j) { s[j] = f2bf(a[j]); s[4 + j] = f2bf(b[j]); }
  *(short8*)&g_wbf[off] = s;
}

// ---------------------------------------------------------------------------
// proj: 256x256 tile, BK=64 (8 steps), 8 waves. Halves the 16-barrier
// overhead of the R9 structure (audit: ~2.5K cyc/step fixed cost).
// A: global->reg f32 single buffer (32 f32) -> pack bf16 -> LDS
//    [32 fp][256 tok] u32 (two 16-row k-halves), R9 keyw/keyr XOR layout.
// B: global_load_lds, 2 slots x (two BK=32 tile_off sub-tiles).
// Schedule per step: [bar] ISSUE_B(t+1) WRITE_A(t+1) ISSUE_A(t+2) COMPUTE(t);
// every slot overwrite is barrier-separated from its readers.
// WAITVM(0)/step is free: loads fly one full step (~4-5K cyc) >> 900-cyc HBM.
// LDS 128KB (1 block/CU - already reg-capped there). Regs: same as R9.
// ---------------------------------------------------------------------------
__global__ __launch_bounds__(512, 2) void proj_kernel(
    const float* __restrict__ Xq, const float* __restrict__ Xk,
    const float* __restrict__ Xv, const float* __restrict__ Bfull,
    short* __restrict__ Oq, short* __restrict__ Ok, short* __restrict__ Ov)
{
  const int wg  = blockIdx.x;
  const int swz = (wg & 7) * 96 + (wg >> 3);
  const int z = swz >> 8, rr = swz & 255;
  const int e0 = (rr & 1) << 8, tok0 = (rr >> 1) << 8;

  const float* X  = (z == 0) ? Xq : (z == 1) ? Xk : Xv;
  const short* Wz = g_wbf + z * (E_DIM * E_DIM);
  const float* bias = Bfull + z * E_DIM;
  short* O = (z == 0) ? Oq : (z == 1) ? Ok : Ov;

  const int b   = tok0 >> 12;
  const int hw0 = tok0 & (HW - 1);
  const float* Xb = X + (size_t)b * E_DIM * HW + hw0;

  __shared__ unsigned ldsA[2 * 8192];    // 2 slots: [32 fp][256 tok] u32 (32KB)
  __shared__ short    ldsB[2 * 16384];   // 2 slots: 2 x (256x32 tile_off) (32KB)

  const int tid = threadIdx.x, lane = tid & 63, wv = tid >> 6;
  const int wm = wv >> 2, wn = wv & 3;
  const int lr = lane & 15, lg = lane >> 4;

  // ---- A staging: thread covers f-rows (2fp,2fp+1) and (2fp+32,2fp+33),
  // tokens hw8..hw8+7
  const int fp  = tid >> 5;            // 0..15
  const int hw8 = (tid & 31) * 8;
  const float* arow0 = Xb + (size_t)(2 * fp) * HW + hw8;
  const float* arow1 = Xb + (size_t)(2 * fp + 32) * HW + hw8;
  const int keyw = ((fp >> 3) & 1) << 4;
  const int aWb0 = fp * 256 + (hw8 ^ keyw);          // kh=0 u32-row
  const int aWb1 = (16 + fp) * 256 + (hw8 ^ keyw);   // kh=1 (same key: +16 rows = +2 on bit3-group, parity preserved)

  // ---- B staging map (inverse of tile_off; rule #21)
  int r0, k0c, r1, k1c;
  chunk_map(tid, r0, k0c);
  chunk_map(512 + tid, r1, k1c);
  const short* sB0 = Wz + (size_t)(e0 + r0) * E_DIM + k0c * 8;
  const short* sB1 = Wz + (size_t)(e0 + r1) * E_DIM + k1c * 8;
  const int dc0 = (wv * 64) * 8, dc1 = (512 + wv * 64) * 8;

  // ---- fragment read offsets (R9 algebra; kh adds +4096 u32 / +8192 shorts)
  const int keyr = (lg >> 1) << 4;
  int aoff[8], boff[4];
#pragma unroll
  for (int i = 0; i < 8; ++i)
    aoff[i] = lg * 1024 + ((wm * 128 + i * 16 + lr) ^ keyr);
#pragma unroll
  for (int j = 0; j < 4; ++j) boff[j] = tile_off(wn * 64 + j * 16 + lr, lg);

  f32x4 acc[8][4];
#pragma unroll
  for (int i = 0; i < 8; ++i)
#pragma unroll
    for (int j = 0; j < 4; ++j) acc[i][j] = (f32x4){0.f, 0.f, 0.f, 0.f};

  f32x4 ar[8];   // single A buffer: 32 f32 (same budget as R9's aX+aY)

#define ISSUE_A(kt) do { \
    const float* ap0 = arow0 + (size_t)(kt) * (64 * HW); \
    const float* ap1 = arow1 + (size_t)(kt) * (64 * HW); \
    ar[0] = *(const f32x4*)(ap0);      ar[1] = *(const f32x4*)(ap0 + 4); \
    ar[2] = *(const f32x4*)(ap0 + HW); ar[3] = *(const f32x4*)(ap0 + 4 + HW); \
    ar[4] = *(const f32x4*)(ap1);      ar[5] = *(const f32x4*)(ap1 + 4); \
    ar[6] = *(const f32x4*)(ap1 + HW); ar[7] = *(const f32x4*)(ap1 + 4 + HW); \
  } while (0)

#define ISSUE_B(slot, kt) do { \
    const int ko = (kt) * 64; \
    GLOAD16(sB0 + ko,      &ldsB[(slot) * 16384 + dc0]); \
    GLOAD16(sB1 + ko,      &ldsB[(slot) * 16384 + dc1]); \
    GLOAD16(sB0 + ko + 32, &ldsB[(slot) * 16384 + 8192 + dc0]); \
    GLOAD16(sB1 + ko + 32, &ldsB[(slot) * 16384 + 8192 + dc1]); \
  } while (0)

#define WRITE_A(slot) do { \
    unsigned* dA0 = &ldsA[(slot) * 8192 + aWb0]; \
    uint4v lo_, hi_; \
    _Pragma("unroll") \
    for (int j = 0; j < 4; ++j) { \
      lo_[j] = pack_bf2(ar[0][j], ar[2][j]); \
      hi_[j] = pack_bf2(ar[1][j], ar[3][j]); \
    } \
    *(uint4v*)(dA0) = lo_;  *(uint4v*)(dA0 + 4) = hi_; \
    unsigned* dA1 = &ldsA[(slot) * 8192 + aWb1]; \
    _Pragma("unroll") \
    for (int j = 0; j < 4; ++j) { \
      lo_[j] = pack_bf2(ar[4][j], ar[6][j]); \
      hi_[j] = pack_bf2(ar[5][j], ar[7][j]); \
    } \
    *(uint4v*)(dA1) = lo_;  *(uint4v*)(dA1 + 4) = hi_; \
  } while (0)

#define COMPUTE(slot) do { \
    const unsigned* pa = ldsA + (slot) * 8192; \
    const short*    pb = ldsB + (slot) * 16384; \
    _Pragma("unroll") \
    for (int kh = 0; kh < 2; ++kh) { \
      const unsigned* pak = pa + kh * 4096; \
      const short*    pbk = pb + kh * 8192; \
      short8 af[8], bf[4]; \
      _Pragma("unroll") \
      for (int i = 0; i < 8; ++i) { \
        union { unsigned u[4]; short8 s; } av_; \
        av_.u[0] = pak[aoff[i]];       av_.u[1] = pak[aoff[i] + 256]; \
        av_.u[2] = pak[aoff[i] + 512]; av_.u[3] = pak[aoff[i] + 768]; \
        af[i] = av_.s; \
      } \
      _Pragma("unroll") \
      for (int j = 0; j < 4; ++j) bf[j] = *(const short8*)(pbk + boff[j]); \
      __builtin_amdgcn_s_setprio(1); \
      _Pragma("unroll") \
      for (int i = 0; i < 8; ++i) \
        _Pragma("unroll") \
        for (int j = 0; j < 4; ++j) \
          acc[i][j] = __builtin_amdgcn_mfma_f32_16x16x32_bf16(af[i], bf[j], acc[i][j], 0, 0, 0); \
      __builtin_amdgcn_s_setprio(0); \
    } \
  } while (0)

  // ---- prologue
  ISSUE_B(0, 0);
  ISSUE_A(0);
  WAITVM(0);           // B(0) landed, A(0) regs ready
  WRITE_A(0);
  ISSUE_A(1);
  LGKM0(); FULL_BAR(); // A(0) visible

  // ---- t = 0  (B(1) first issued here; WRITE_A(1) waits on A(1) via compiler)
  ISSUE_B(1, 1);
  WRITE_A(1);
  ISSUE_A(2);
  COMPUTE(0);

  // ---- t = 1..5 (steady)
  for (int k = 0; k < 5; ++k) {
    const int t = k + 1;
    const int sc = t & 1, sn = (t + 1) & 1;
    WAITVM(0); LGKM0(); FULL_BAR();   // B(t+1)... wait: retires B(t+1)? see note
    ISSUE_B(sn, t + 1);               // post-barrier: B(t-1)'s readers done
    WRITE_A(sn);                      // regs = A(t+1)
    ISSUE_A(t + 2);
    COMPUTE(sc);
  }

  // ---- t = 6
  WAITVM(0); LGKM0(); FULL_BAR();
  ISSUE_B(1, 7);
  WRITE_A(1);          // A(7), issued at t=5
  COMPUTE(0);
  // ---- t = 7
  WAITVM(0); LGKM0(); FULL_BAR();
  COMPUTE(1);

#undef ISSUE_A
#undef ISSUE_B
#undef WRITE_A
#undef COMPUTE

  // epilogue: bias + bf16, scatter into window-token layout
  float bj[4];
#pragma unroll
  for (int j = 0; j < 4; ++j) bj[j] = bias[e0 + wn * 64 + j * 16 + lr];
#pragma unroll
  for (int i = 0; i < 8; ++i) {
#pragma unroll
    for (int r = 0; r < 4; ++r) {
      const int token = tok0 + wm * 128 + i * 16 + lg * 4 + r;
      const int hw = token & (HW - 1);
      const int h = hw >> 6, w = hw & 63;
      const int nwin = ((token >> 12) << 6) + ((h >> 3) << 3) + (w >> 3);
      const int twin = ((h & 7) << 3) + (w & 7);
      short* orow = O + ((size_t)(nwin * 64 + twin) << 9) + e0 + wn * 64 + lr;
#pragma unroll
      for (int j = 0; j < 4; ++j)
        orow[j * 16] = f2bf(acc[i][j][r] + bj[j]);
    }
  }
}

// ---------------------------------------------------------------------------
// attn: one block (4 waves) per (head, window)  [R9-proven]
// ---------------------------------------------------------------------------
__global__ __launch_bounds__(256) void attn_kernel(
    const short* __restrict__ Qp, const short* __restrict__ Kp,
    const short* __restrict__ Vp, short* __restrict__ Ob)
{
  const int head = blockIdx.x, nwin = blockIdx.y;
  const int base = nwin * (64 * E_DIM) + head * 64;

  __shared__ short lQ[64 * 64];
  __shared__ short lK[64 * 64];
  __shared__ short lVT[64 * 64];

  const int tid = threadIdx.x;
  {
    const int row = tid >> 2, sg = (tid & 3) * 16;
    const int go = base + row * E_DIM + sg;
    *(short8*)&lQ[swzidx(row, sg)]     = *(const short8*)&Qp[go];
    *(short8*)&lQ[swzidx(row, sg + 8)] = *(const short8*)&Qp[go + 8];
    *(short8*)&lK[swzidx(row, sg)]     = *(const short8*)&Kp[go];
    *(short8*)&lK[swzidx(row, sg + 8)] = *(const short8*)&Kp[go + 8];
    const int tv = tid & 63, d0 = (tid >> 6) * 16;
    const int gv = base + tv * E_DIM + d0;
    short8 v0 = *(const short8*)&Vp[gv];
    short8 v1 = *(const short8*)&Vp[gv + 8];
#pragma unroll
    for (int ii = 0; ii < 8; ++ii) lVT[swzidx(d0 + ii, tv)] = v0[ii];
#pragma unroll
    for (int ii = 0; ii < 8; ++ii) lVT[swzidx(d0 + 8 + ii, tv)] = v1[ii];
  }
  __syncthreads();

  const int lane = tid & 63, wv = tid >> 6;
  const int lr = lane & 15, lg = lane >> 4;
  const int m0 = wv * 16;

  f32x4 s[4];
#pragma unroll
  for (int j = 0; j < 4; ++j) s[j] = (f32x4){0.f, 0.f, 0.f, 0.f};
#pragma unroll
  for (int ks = 0; ks < 2; ++ks) {
    const int kk = ks * 32 + lg * 8;
    short8 a = *(const short8*)&lQ[swzidx(m0 + lr, kk)];
#pragma unroll
    for (int j = 0; j < 4; ++j) {
      short8 b = *(const short8*)&lK[swzidx(j * 16 + lr, kk)];
      s[j] = __builtin_amdgcn_mfma_f32_16x16x32_bf16(a, b, s[j], 0, 0, 0);
    }
  }

  const float cexp = 0.125f * 1.4426950408889634f;
  float p[4][4], rs[4];
#pragma unroll
  for (int r = 0; r < 4; ++r) {
    float mx = fmaxf(fmaxf(s[0][r], s[1][r]), fmaxf(s[2][r], s[3][r]));
    mx = fmaxf(mx, __shfl_xor(mx, 1));
    mx = fmaxf(mx, __shfl_xor(mx, 2));
    mx = fmaxf(mx, __shfl_xor(mx, 4));
    mx = fmaxf(mx, __shfl_xor(mx, 8));
    float sm = 0.f;
#pragma unroll
    for (int j = 0; j < 4; ++j) { p[j][r] = exp2f((s[j][r] - mx) * cexp); sm += p[j][r]; }
    sm += __shfl_xor(sm, 1); sm += __shfl_xor(sm, 2);
    sm += __shfl_xor(sm, 4); sm += __shfl_xor(sm, 8);
    rs[r] = 1.0f / sm;
  }

#pragma unroll
  for (int r = 0; r < 4; ++r)
#pragma unroll
    for (int j = 0; j < 4; ++j)
      lQ[swzidx(m0 + lg * 4 + r, j * 16 + lr)] = f2bf(p[j][r]);

  f32x4 o[4];
#pragma unroll
  for (int nf = 0; nf < 4; ++nf) o[nf] = (f32x4){0.f, 0.f, 0.f, 0.f};
#pragma unroll
  for (int ks = 0; ks < 2; ++ks) {
    const int kk = ks * 32 + lg * 8;
    short8 a = *(const short8*)&lQ[swzidx(m0 + lr, kk)];
#pragma unroll
    for (int nf = 0; nf < 4; ++nf) {
      short8 b = *(const short8*)&lVT[swzidx(nf * 16 + lr, kk)];
      o[nf] = __builtin_amdgcn_mfma_f32_16x16x32_bf16(a, b, o[nf], 0, 0, 0);
    }
  }

#pragma unroll
  for (int r = 0; r < 4; ++r) {
    const int t = m0 + lg * 4 + r;
    short* orow = Ob + base + t * E_DIM + lr;
#pragma unroll
    for (int nf = 0; nf < 4; ++nf)
      orow[nf * 16] = f2bf(o[nf][r] * rs[r]);
  }
}

// ---------------------------------------------------------------------------
// oproj: C[e, tok] = Wo[e,:] . o[tok,:] + bo[e]; 4-slot gload_lds ring
// ---------------------------------------------------------------------------
__global__ __launch_bounds__(512, 2) void oproj_kernel(
    const short* __restrict__ Ob, const float* __restrict__ bo,
    float* __restrict__ Out)
{
  const int wg  = blockIdx.x;                 // 256 = 8 * 32
  const int swz = (wg & 7) * 32 + (wg >> 3);
  const int e0 = (swz & 1) << 8, tok0 = (swz >> 1) << 8;
  const short* Wo = g_wbf + 1536 * E_DIM;

  __shared__ short lds[4 * 16384];

  const int tid = threadIdx.x, lane = tid & 63, wv = tid >> 6;
  const int wm = wv >> 2, wn = wv & 3;
  const int lr = lane & 15, lg = lane >> 4;

  int r0, k0c, r1, k1c;
  chunk_map(tid, r0, k0c);
  chunk_map(512 + tid, r1, k1c);
  const short* sA0 = Wo + (size_t)(e0 + r0) * E_DIM + k0c * 8;
  const short* sA1 = Wo + (size_t)(e0 + r1) * E_DIM + k1c * 8;
  const short* sB0 = Ob + (size_t)(tok0 + r0) * E_DIM + k0c * 8;
  const short* sB1 = Ob + (size_t)(tok0 + r1) * E_DIM + k1c * 8;
  const int dc0 = (wv * 64) * 8, dc1 = (512 + wv * 64) * 8;

  int aoff[8], boff[4];
#pragma unroll
  for (int i = 0; i < 8; ++i) aoff[i] = tile_off(wm * 128 + i * 16 + lr, lg);
#pragma unroll
  for (int j = 0; j < 4; ++j) boff[j] = 8192 + tile_off(wn * 64 + j * 16 + lr, lg);

  f32x4 acc[8][4];
#pragma unroll
  for (int i = 0; i < 8; ++i)
#pragma unroll
    for (int j = 0; j < 4; ++j) acc[i][j] = (f32x4){0.f, 0.f, 0.f, 0.f};

  auto STAGE = [&](int slot, int kt) {
    const int sb = slot * 16384, ko = kt * 32;
    GLOAD16(sA0 + ko, &lds[sb + dc0]);
    GLOAD16(sA1 + ko, &lds[sb + dc1]);
    GLOAD16(sB0 + ko, &lds[sb + 8192 + dc0]);
    GLOAD16(sB1 + ko, &lds[sb + 8192 + dc1]);
  };
  auto COMPUTE = [&](int slot) {
    const int sb = slot * 16384;
    short8 af[8], bf[4];
#pragma unroll
    for (int i = 0; i < 8; ++i) af[i] = *(const short8*)&lds[sb + aoff[i]];
#pragma unroll
    for (int j = 0; j < 4; ++j) bf[j] = *(const short8*)&lds[sb + boff[j]];
    __builtin_amdgcn_s_setprio(1);
#pragma unroll
    for (int i = 0; i < 8; ++i)
#pragma unroll
      for (int j = 0; j < 4; ++j)
        acc[i][j] = __builtin_amdgcn_mfma_f32_16x16x32_bf16(af[i], bf[j], acc[i][j], 0, 0, 0);
    __builtin_amdgcn_s_setprio(0);
  };

  STAGE(0, 0); STAGE(1, 1); STAGE(2, 2);
  for (int t = 0; t < 13; ++t) {
    WAITVM(8);
    FULL_BAR();
    STAGE((t + 3) & 3, t + 3);
    COMPUTE(t & 3);
  }
  WAITVM(8); FULL_BAR(); COMPUTE(13 & 3);
  WAITVM(4); FULL_BAR(); COMPUTE(14 & 3);
  WAITVM(0); FULL_BAR(); COMPUTE(15 & 3);

#pragma unroll
  for (int i = 0; i < 8; ++i) {
#pragma unroll
    for (int r = 0; r < 4; ++r) {
      const int e = e0 + wm * 128 + i * 16 + lg * 4 + r;
      const float be = bo[e];
#pragma unroll
      for (int j = 0; j < 4; ++j) {
        const int wtok = tok0 + wn * 64 + j * 16 + lr;
        const int n = wtok >> 6, t = wtok & 63;
        const int b = n >> 6;
        const int h = (((n >> 3) & 7) << 3) + (t >> 3);
        const int w = ((n & 7) << 3) + (t & 7);
        Out[(size_t)b * (E_DIM * HW) + (size_t)e * HW + (h << 6) + w] =
            acc[i][j][r] + be;
      }
    }
  }
}

// ---------------------------------------------------------------------------
extern "C" void kernel_launch(void* const* d_in, const int* in_sizes, int n_in,
                              void* d_out, int out_size, void* d_ws, size_t ws_size,
                              hipStream_t stream) {
  const float* q     = (const float*)d_in[0];
  const float* k     = (const float*)d_in[1];
  const float* v     = (const float*)d_in[2];
  const float* in_w  = (const float*)d_in[3];
  const float* in_b  = (const float*)d_in[4];
  const float* out_w = (const float*)d_in[5];
  const float* out_b = (const float*)d_in[6];
  float* out = (float*)d_out;

  // d_ws: qp @0, kp @32Mi, vp @64Mi, ob @96Mi (4 x 32 MiB bf16)
  short* qp = (short*)d_ws;
  short* kp = qp + NTE;
  short* vp = kp + NTE;
  short* ob = vp + NTE;

  convert_w<<<512, 256, 0, stream>>>(in_w, out_w);
  proj_kernel<<<768, 512, 0, stream>>>(q, k, v, in_b, qp, kp, vp);
  attn_kernel<<<dim3(8, 512), 256, 0, stream>>>(qp, kp, vp, ob);
  oproj_kernel<<<256, 512, 0, stream>>>(ob, out_b, out);
}

// Round 18
// 161.122 us; speedup vs baseline: 1.2458x; 1.1459x over previous
//
#include <hip/hip_runtime.h>

typedef __attribute__((ext_vector_type(4))) float f32x4;
typedef __attribute__((ext_vector_type(8))) short short8;
typedef __attribute__((ext_vector_type(4))) unsigned uint4v;

#define E_DIM 512
#define HW    4096      // 64*64 spatial per batch
#define NT    32768     // total tokens
#define NTE   16777216  // NT*E_DIM elements (32 MiB as bf16)

// bf16 copies of in_proj_w (rows 0..1535) and out_proj_w (rows 1536..2047)
__device__ short g_wbf[2048 * E_DIM];

// round-to-nearest-even f32 -> bf16 bits
__device__ __forceinline__ short f2bf(float f) {
  union { float f; unsigned u; } v; v.f = f;
  unsigned u = v.u;
  u += 0x7fffu + ((u >> 16) & 1u);
  return (short)(u >> 16);
}
__device__ __forceinline__ unsigned pack_bf2(float lo, float hi) {
  return (unsigned)(unsigned short)f2bf(lo) | ((unsigned)(unsigned short)f2bf(hi) << 16);
}

// attn-kernel swizzle: [rows][64] bf16 tile, chunk ^= (row&7)
__device__ __forceinline__ int swzidx(int row, int k) {
  return row * 64 + (k ^ ((row & 7) << 3));
}

// ---- 256x32 bf16 staged tile (gload_lds): 128B lines = 2 rows x 4 chunks,
// physical chunk = logical ^ (line&7)  -> 2-way (free) ds_read_b128 banks
__device__ __forceinline__ void chunk_map(int c, int& row, int& kc) {
  const int line = c >> 3;
  const int l = (c & 7) ^ (line & 7);
  row = line * 2 + (l >> 2);
  kc = l & 3;
}
__device__ __forceinline__ int tile_off(int row, int kc) {  // in shorts
  const int line = row >> 1;
  const int phys = (((row & 1) << 2) | kc) ^ (line & 7);
  return line * 64 + phys * 8;
}

// async global->LDS, 16B per lane; LDS dest = wave-uniform base (+lane*16 HW)
#define GLOAD16(g, l) __builtin_amdgcn_global_load_lds( \
    (const __attribute__((address_space(1))) void*)(g), \
    (__attribute__((address_space(3))) void*)(l), 16, 0, 0)

#define WAITVM(N) asm volatile("s_waitcnt vmcnt(" #N ")" ::: "memory")
#define LGKM0()   asm volatile("s_waitcnt lgkmcnt(0)" ::: "memory")
#define FULL_BAR() do { asm volatile("" ::: "memory"); \
  __builtin_amdgcn_s_barrier(); asm volatile("" ::: "memory"); } while (0)

// ---------------------------------------------------------------------------
// convert_w: f32 -> bf16 for both weight matrices into g_wbf
// ---------------------------------------------------------------------------
__global__ __launch_bounds__(256) void convert_w(
    const float* __restrict__ w_in, const float* __restrict__ w_out)
{
  const size_t off = ((size_t)blockIdx.x * 256 + threadIdx.x) * 8;
  const float* src = (off < 786432) ? (w_in + off) : (w_out + (off - 786432));
  f32x4 a = *(const f32x4*)src, b = *(const f32x4*)(src + 4);
  short8 s;
#pragma unroll
  for (int j = 0; j < 4; ++j) { s[j] = f2bf(a[j]); s[4 + j] = f2bf(b[j]); }
  *(short8*)&g_wbf[off] = s;
}

// ---------------------------------------------------------------------------
// proj: R9-exact best-known (107us; total 161.4). 256x256 tile, BK=32, 8 waves.
// A: global->reg f32 depth-2 (aX/aY) -> pack bf16 -> LDS [fp][tok], 2 slots.
// B: global_load_lds, 3-slot ring, issue-after-barrier 2 tiles ahead.
// FROZEN: all variants measured and worse —
//   R8  (min-waves 4):       spill, 924us
//   R10 (2-slot B):          164us total
//   R13 (depth-3 A):         spill, 191us
//   R14 (b64 write-swizzle): conflicts -20% but flat 110us
//   R15 (128^2 tile TLP):    151us (4x barrier count)
//   R16 (fused tail):        attn_oproj 80us vs 48us split
//   R17 (BK=64):             spill, 131us
// Structural note: acc[8][4]=128 regs -> 2 waves/SIMD -> 1 block/CU; ~2.5K
// cyc/step barrier overhead cannot be hidden; 481 TF is this family's floor.
// ---------------------------------------------------------------------------
__global__ __launch_bounds__(512, 2) void proj_kernel(
    const float* __restrict__ Xq, const float* __restrict__ Xk,
    const float* __restrict__ Xv, const float* __restrict__ Bfull,
    short* __restrict__ Oq, short* __restrict__ Ok, short* __restrict__ Ov)
{
  const int wg  = blockIdx.x;
  const int swz = (wg & 7) * 96 + (wg >> 3);
  const int z = swz >> 8, rr = swz & 255;
  const int e0 = (rr & 1) << 8, tok0 = (rr >> 1) << 8;

  const float* X  = (z == 0) ? Xq : (z == 1) ? Xk : Xv;
  const short* Wz = g_wbf + z * (E_DIM * E_DIM);
  const float* bias = Bfull + z * E_DIM;
  short* O = (z == 0) ? Oq : (z == 1) ? Ok : Ov;

  const int b   = tok0 >> 12;
  const int hw0 = tok0 & (HW - 1);
  const float* Xb = X + (size_t)b * E_DIM * HW + hw0;

  __shared__ unsigned ldsA[2 * 4096];   // 2 slots: [16 fp][256 tok] u32
  __shared__ short    ldsB[3 * 8192];   // 3 slots: 256x32 bf16, tile_off swz

  const int tid = threadIdx.x, lane = tid & 63, wv = tid >> 6;
  const int wm = wv >> 2, wn = wv & 3;
  const int lr = lane & 15, lg = lane >> 4;

  const int fp = tid >> 5;
  const int hw8 = (tid & 31) * 8;
  const float* arow0 = Xb + (size_t)(2 * fp) * HW + hw8;
  const int keyw = (fp >> 3) << 4;
  const int aWbase = fp * 256 + (hw8 ^ keyw);

  int r0, k0c, r1, k1c;
  chunk_map(tid, r0, k0c);
  chunk_map(512 + tid, r1, k1c);
  const short* sB0 = Wz + (size_t)(e0 + r0) * E_DIM + k0c * 8;
  const short* sB1 = Wz + (size_t)(e0 + r1) * E_DIM + k1c * 8;
  const int dc0 = (wv * 64) * 8, dc1 = (512 + wv * 64) * 8;

  const int keyr = (lg >> 1) << 4;
  int aoff[8], boff[4];
#pragma unroll
  for (int i = 0; i < 8; ++i)
    aoff[i] = lg * 1024 + ((wm * 128 + i * 16 + lr) ^ keyr);
#pragma unroll
  for (int j = 0; j < 4; ++j) boff[j] = tile_off(wn * 64 + j * 16 + lr, lg);

  f32x4 acc[8][4];
#pragma unroll
  for (int i = 0; i < 8; ++i)
#pragma unroll
    for (int j = 0; j < 4; ++j) acc[i][j] = (f32x4){0.f, 0.f, 0.f, 0.f};

  f32x4 aX[4], aY[4];

#define ISSUE_A(dst, kt) do { \
    const float* ap = arow0 + (size_t)(kt) * (32 * HW); \
    dst[0] = *(const f32x4*)(ap);          dst[1] = *(const f32x4*)(ap + 4); \
    dst[2] = *(const f32x4*)(ap + HW);     dst[3] = *(const f32x4*)(ap + 4 + HW); \
  } while (0)

#define ISSUE_B(slot, kt) do { \
    const int ko2 = (kt) * 32, sb2 = (slot) * 8192; \
    GLOAD16(sB0 + ko2, &ldsB[sb2 + dc0]); \
    GLOAD16(sB1 + ko2, &ldsB[sb2 + dc1]); \
  } while (0)

#define WRITE_A(slot, src) do { \
    unsigned* dA = &ldsA[(slot) * 4096 + aWbase]; \
    uint4v lo_, hi_; \
    _Pragma("unroll") \
    for (int j = 0; j < 4; ++j) { \
      lo_[j] = pack_bf2(src[0][j], src[2][j]); \
      hi_[j] = pack_bf2(src[1][j], src[3][j]); \
    } \
    *(uint4v*)(dA) = lo_; \
    *(uint4v*)(dA + 4) = hi_; \
  } while (0)

#define COMPUTE(aslot, bslot) do { \
    const unsigned* pa = ldsA + (aslot) * 4096; \
    const short*    pb = ldsB + (bslot) * 8192; \
    short8 af[8], bf[4]; \
    _Pragma("unroll") \
    for (int i = 0; i < 8; ++i) { \
      union { unsigned u[4]; short8 s; } av_; \
      av_.u[0] = pa[aoff[i]];       av_.u[1] = pa[aoff[i] + 256]; \
      av_.u[2] = pa[aoff[i] + 512]; av_.u[3] = pa[aoff[i] + 768]; \
      af[i] = av_.s; \
    } \
    _Pragma("unroll") \
    for (int j = 0; j < 4; ++j) bf[j] = *(const short8*)(pb + boff[j]); \
    __builtin_amdgcn_s_setprio(1); \
    _Pragma("unroll") \
    for (int i = 0; i < 8; ++i) \
      _Pragma("unroll") \
      for (int j = 0; j < 4; ++j) \
        acc[i][j] = __builtin_amdgcn_mfma_f32_16x16x32_bf16(af[i], bf[j], acc[i][j], 0, 0, 0); \
    __builtin_amdgcn_s_setprio(0); \
  } while (0)

  ISSUE_B(0, 0);
  ISSUE_B(1, 1);
  ISSUE_A(aX, 0);
  ISSUE_A(aY, 1);
  WAITVM(4);
  WRITE_A(0, aX);

  ISSUE_A(aX, 2);
  WAITVM(4); LGKM0();
  FULL_BAR();
  ISSUE_B(2, 2);
  WRITE_A(1, aY);
  COMPUTE(0, 0);

  for (int k = 0; k < 6; ++k) {
    const int t = 2 * k + 1;
    ISSUE_A(aY, t + 2);
    WAITVM(6); LGKM0();
    FULL_BAR();
    ISSUE_B((t + 2) % 3, t + 2);
    WRITE_A(0, aX);
    COMPUTE(1, t % 3);
    ISSUE_A(aX, t + 3);
    WAITVM(6); LGKM0();
    FULL_BAR();
    ISSUE_B((t + 3) % 3, t + 3);
    WRITE_A(1, aY);
    COMPUTE(0, (t + 1) % 3);
  }

  ISSUE_A(aY, 15);
  WAITVM(6); LGKM0();
  FULL_BAR();
  ISSUE_B(0, 15);
  WRITE_A(0, aX);
  COMPUTE(1, 1);
  WAITVM(2); LGKM0();
  FULL_BAR();
  WRITE_A(1, aY);
  COMPUTE(0, 2);
  WAITVM(0); LGKM0();
  FULL_BAR();
  COMPUTE(1, 0);

#undef ISSUE_A
#undef ISSUE_B
#undef WRITE_A
#undef COMPUTE

  float bj[4];
#pragma unroll
  for (int j = 0; j < 4; ++j) bj[j] = bias[e0 + wn * 64 + j * 16 + lr];
#pragma unroll
  for (int i = 0; i < 8; ++i) {
#pragma unroll
    for (int r = 0; r < 4; ++r) {
      const int token = tok0 + wm * 128 + i * 16 + lg * 4 + r;
      const int hw = token & (HW - 1);
      const int h = hw >> 6, w = hw & 63;
      const int nwin = ((token >> 12) << 6) + ((h >> 3) << 3) + (w >> 3);
      const int twin = ((h & 7) << 3) + (w & 7);
      short* orow = O + ((size_t)(nwin * 64 + twin) << 9) + e0 + wn * 64 + lr;
#pragma unroll
      for (int j = 0; j < 4; ++j)
        orow[j * 16] = f2bf(acc[i][j][r] + bj[j]);
    }
  }
}

// ---------------------------------------------------------------------------
// attn: one block (4 waves) per (head, window)
// ---------------------------------------------------------------------------
__global__ __launch_bounds__(256) void attn_kernel(
    const short* __restrict__ Qp, const short* __restrict__ Kp,
    const short* __restrict__ Vp, short* __restrict__ Ob)
{
  const int head = blockIdx.x, nwin = blockIdx.y;
  const int base = nwin * (64 * E_DIM) + head * 64;

  __shared__ short lQ[64 * 64];
  __shared__ short lK[64 * 64];
  __shared__ short lVT[64 * 64];

  const int tid = threadIdx.x;
  {
    const int row = tid >> 2, sg = (tid & 3) * 16;
    const int go = base + row * E_DIM + sg;
    *(short8*)&lQ[swzidx(row, sg)]     = *(const short8*)&Qp[go];
    *(short8*)&lQ[swzidx(row, sg + 8)] = *(const short8*)&Qp[go + 8];
    *(short8*)&lK[swzidx(row, sg)]     = *(const short8*)&Kp[go];
    *(short8*)&lK[swzidx(row, sg + 8)] = *(const short8*)&Kp[go + 8];
    const int tv = tid & 63, d0 = (tid >> 6) * 16;
    const int gv = base + tv * E_DIM + d0;
    short8 v0 = *(const short8*)&Vp[gv];
    short8 v1 = *(const short8*)&Vp[gv + 8];
#pragma unroll
    for (int ii = 0; ii < 8; ++ii) lVT[swzidx(d0 + ii, tv)] = v0[ii];
#pragma unroll
    for (int ii = 0; ii < 8; ++ii) lVT[swzidx(d0 + 8 + ii, tv)] = v1[ii];
  }
  __syncthreads();

  const int lane = tid & 63, wv = tid >> 6;
  const int lr = lane & 15, lg = lane >> 4;
  const int m0 = wv * 16;

  f32x4 s[4];
#pragma unroll
  for (int j = 0; j < 4; ++j) s[j] = (f32x4){0.f, 0.f, 0.f, 0.f};
#pragma unroll
  for (int ks = 0; ks < 2; ++ks) {
    const int kk = ks * 32 + lg * 8;
    short8 a = *(const short8*)&lQ[swzidx(m0 + lr, kk)];
#pragma unroll
    for (int j = 0; j < 4; ++j) {
      short8 b = *(const short8*)&lK[swzidx(j * 16 + lr, kk)];
      s[j] = __builtin_amdgcn_mfma_f32_16x16x32_bf16(a, b, s[j], 0, 0, 0);
    }
  }

  const float cexp = 0.125f * 1.4426950408889634f;
  float p[4][4], rs[4];
#pragma unroll
  for (int r = 0; r < 4; ++r) {
    float mx = fmaxf(fmaxf(s[0][r], s[1][r]), fmaxf(s[2][r], s[3][r]));
    mx = fmaxf(mx, __shfl_xor(mx, 1));
    mx = fmaxf(mx, __shfl_xor(mx, 2));
    mx = fmaxf(mx, __shfl_xor(mx, 4));
    mx = fmaxf(mx, __shfl_xor(mx, 8));
    float sm = 0.f;
#pragma unroll
    for (int j = 0; j < 4; ++j) { p[j][r] = exp2f((s[j][r] - mx) * cexp); sm += p[j][r]; }
    sm += __shfl_xor(sm, 1); sm += __shfl_xor(sm, 2);
    sm += __shfl_xor(sm, 4); sm += __shfl_xor(sm, 8);
    rs[r] = 1.0f / sm;
  }

#pragma unroll
  for (int r = 0; r < 4; ++r)
#pragma unroll
    for (int j = 0; j < 4; ++j)
      lQ[swzidx(m0 + lg * 4 + r, j * 16 + lr)] = f2bf(p[j][r]);

  f32x4 o[4];
#pragma unroll
  for (int nf = 0; nf < 4; ++nf) o[nf] = (f32x4){0.f, 0.f, 0.f, 0.f};
#pragma unroll
  for (int ks = 0; ks < 2; ++ks) {
    const int kk = ks * 32 + lg * 8;
    short8 a = *(const short8*)&lQ[swzidx(m0 + lr, kk)];
#pragma unroll
    for (int nf = 0; nf < 4; ++nf) {
      short8 b = *(const short8*)&lVT[swzidx(nf * 16 + lr, kk)];
      o[nf] = __builtin_amdgcn_mfma_f32_16x16x32_bf16(a, b, o[nf], 0, 0, 0);
    }
  }

#pragma unroll
  for (int r = 0; r < 4; ++r) {
    const int t = m0 + lg * 4 + r;
    short* orow = Ob + base + t * E_DIM + lr;
#pragma unroll
    for (int nf = 0; nf < 4; ++nf)
      orow[nf * 16] = f2bf(o[nf][r] * rs[r]);
  }
}

// ---------------------------------------------------------------------------
// oproj: C[e, tok] = Wo[e,:] . o[tok,:] + bo[e]; 4-slot gload_lds ring
// ---------------------------------------------------------------------------
__global__ __launch_bounds__(512, 2) void oproj_kernel(
    const short* __restrict__ Ob, const float* __restrict__ bo,
    float* __restrict__ Out)
{
  const int wg  = blockIdx.x;                 // 256 = 8 * 32
  const int swz = (wg & 7) * 32 + (wg >> 3);
  const int e0 = (swz & 1) << 8, tok0 = (swz >> 1) << 8;
  const short* Wo = g_wbf + 1536 * E_DIM;

  __shared__ short lds[4 * 16384];

  const int tid = threadIdx.x, lane = tid & 63, wv = tid >> 6;
  const int wm = wv >> 2, wn = wv & 3;
  const int lr = lane & 15, lg = lane >> 4;

  int r0, k0c, r1, k1c;
  chunk_map(tid, r0, k0c);
  chunk_map(512 + tid, r1, k1c);
  const short* sA0 = Wo + (size_t)(e0 + r0) * E_DIM + k0c * 8;
  const short* sA1 = Wo + (size_t)(e0 + r1) * E_DIM + k1c * 8;
  const short* sB0 = Ob + (size_t)(tok0 + r0) * E_DIM + k0c * 8;
  const short* sB1 = Ob + (size_t)(tok0 + r1) * E_DIM + k1c * 8;
  const int dc0 = (wv * 64) * 8, dc1 = (512 + wv * 64) * 8;

  int aoff[8], boff[4];
#pragma unroll
  for (int i = 0; i < 8; ++i) aoff[i] = tile_off(wm * 128 + i * 16 + lr, lg);
#pragma unroll
  for (int j = 0; j < 4; ++j) boff[j] = 8192 + tile_off(wn * 64 + j * 16 + lr, lg);

  f32x4 acc[8][4];
#pragma unroll
  for (int i = 0; i < 8; ++i)
#pragma unroll
    for (int j = 0; j < 4; ++j) acc[i][j] = (f32x4){0.f, 0.f, 0.f, 0.f};

  auto STAGE = [&](int slot, int kt) {
    const int sb = slot * 16384, ko = kt * 32;
    GLOAD16(sA0 + ko, &lds[sb + dc0]);
    GLOAD16(sA1 + ko, &lds[sb + dc1]);
    GLOAD16(sB0 + ko, &lds[sb + 8192 + dc0]);
    GLOAD16(sB1 + ko, &lds[sb + 8192 + dc1]);
  };
  auto COMPUTE = [&](int slot) {
    const int sb = slot * 16384;
    short8 af[8], bf[4];
#pragma unroll
    for (int i = 0; i < 8; ++i) af[i] = *(const short8*)&lds[sb + aoff[i]];
#pragma unroll
    for (int j = 0; j < 4; ++j) bf[j] = *(const short8*)&lds[sb + boff[j]];
    __builtin_amdgcn_s_setprio(1);
#pragma unroll
    for (int i = 0; i < 8; ++i)
#pragma unroll
      for (int j = 0; j < 4; ++j)
        acc[i][j] = __builtin_amdgcn_mfma_f32_16x16x32_bf16(af[i], bf[j], acc[i][j], 0, 0, 0);
    __builtin_amdgcn_s_setprio(0);
  };

  STAGE(0, 0); STAGE(1, 1); STAGE(2, 2);
  for (int t = 0; t < 13; ++t) {
    WAITVM(8);
    FULL_BAR();
    STAGE((t + 3) & 3, t + 3);
    COMPUTE(t & 3);
  }
  WAITVM(8); FULL_BAR(); COMPUTE(13 & 3);
  WAITVM(4); FULL_BAR(); COMPUTE(14 & 3);
  WAITVM(0); FULL_BAR(); COMPUTE(15 & 3);

#pragma unroll
  for (int i = 0; i < 8; ++i) {
#pragma unroll
    for (int r = 0; r < 4; ++r) {
      const int e = e0 + wm * 128 + i * 16 + lg * 4 + r;
      const float be = bo[e];
#pragma unroll
      for (int j = 0; j < 4; ++j) {
        const int wtok = tok0 + wn * 64 + j * 16 + lr;
        const int n = wtok >> 6, t = wtok & 63;
        const int b = n >> 6;
        const int h = (((n >> 3) & 7) << 3) + (t >> 3);
        const int w = ((n & 7) << 3) + (t & 7);
        Out[(size_t)b * (E_DIM * HW) + (size_t)e * HW + (h << 6) + w] =
            acc[i][j][r] + be;
      }
    }
  }
}

// ---------------------------------------------------------------------------
extern "C" void kernel_launch(void* const* d_in, const int* in_sizes, int n_in,
                              void* d_out, int out_size, void* d_ws, size_t ws_size,
                              hipStream_t stream) {
  const float* q     = (const float*)d_in[0];
  const float* k     = (const float*)d_in[1];
  const float* v     = (const float*)d_in[2];
  const float* in_w  = (const float*)d_in[3];
  const float* in_b  = (const float*)d_in[4];
  const float* out_w = (const float*)d_in[5];
  const float* out_b = (const float*)d_in[6];
  float* out = (float*)d_out;

  // d_ws: qp @0, kp @32Mi, vp @64Mi, ob @96Mi (4 x 32 MiB bf16)
  short* qp = (short*)d_ws;
  short* kp = qp + NTE;
  short* vp = kp + NTE;
  short* ob = vp + NTE;

  convert_w<<<512, 256, 0, stream>>>(in_w, out_w);
  proj_kernel<<<768, 512, 0, stream>>>(q, k, v, in_b, qp, kp, vp);
  attn_kernel<<<dim3(8, 512), 256, 0, stream>>>(qp, kp, vp, ob);
  oproj_kernel<<<256, 512, 0, stream>>>(ob, out_b, out);
}